// Round 12
// baseline (495.744 us; speedup 1.0000x reference)
//
#include <hip/hip_runtime.h>

typedef short bf16x8 __attribute__((ext_vector_type(8)));
typedef float f32x4 __attribute__((ext_vector_type(4)));

#define NROWS 131072L
#define DIN 1024
#define DEMB 512
#define NEXT 640   // extended B rows: 512 emb + 34 folded-head + zero tail

__device__ __forceinline__ unsigned short f2bf(float f) {
  unsigned u = __float_as_uint(f);
  u += 0x7FFFu + ((u >> 16) & 1u);
  return (unsigned short)(u >> 16);
}

// Pack two f32 -> two bf16 (round-half-up): 2 adds + 1 v_perm_b32 (R5+-proven).
__device__ __forceinline__ unsigned pkhi(float a, float b) {
  unsigned ua = __float_as_uint(a) + 0x8000u;
  unsigned ub = __float_as_uint(b) + 0x8000u;
  return __builtin_amdgcn_perm(ub, ua, 0x07060302u);
}

__device__ __forceinline__ float softplusf(float v) {
  return fmaxf(v, 0.f) + log1pf(expf(-fabsf(v)));
}

// ---------- kernel 0: Wb (1024x512 f32) -> WbT rows 0..511 (bf16, k-contig) ----------
__global__ __launch_bounds__(256) void wb_transpose(const float* __restrict__ Wb,
                                                    unsigned short* __restrict__ WbT) {
  int g = blockIdx.x * 256 + threadIdx.x;
  int n = g & 511;
  int kb = g >> 9;
  unsigned short tmp[8];
#pragma unroll
  for (int j = 0; j < 8; ++j)
    tmp[j] = f2bf(Wb[(kb * 8 + j) * DEMB + n]);
  uint4 v;
  v.x = (unsigned)tmp[0] | ((unsigned)tmp[1] << 16);
  v.y = (unsigned)tmp[2] | ((unsigned)tmp[3] << 16);
  v.z = (unsigned)tmp[4] | ((unsigned)tmp[5] << 16);
  v.w = (unsigned)tmp[6] | ((unsigned)tmp[7] << 16);
  *(uint4*)(WbT + (long)n * DIN + kb * 8) = v;
}

// ---------- kernel 0b: zero rows 546..639 of WbT_ext ----------
__global__ void zero_tail(unsigned* __restrict__ p) {
  p[blockIdx.x * 256 + threadIdx.x] = 0u;
}

// ---------- kernel 0c: WbT rows 512..545 = (Wb @ W34)^T ----------
__global__ __launch_bounds__(256) void wfold_rows(const float* __restrict__ Wb,
                                                  const float* __restrict__ Wp,
                                                  const float* __restrict__ Ws,
                                                  unsigned short* __restrict__ WbT) {
  int w = threadIdx.x >> 6, lane = threadIdx.x & 63;
  int k = blockIdx.x * 4 + w;
  if (lane >= 34) return;
  const float* src;
  if (lane < 2) src = Wp + lane;
  else { int s = (lane - 2) >> 1; src = Ws + s * 1024 + (lane & 1); }
  const float* wrow = Wb + (long)k * DEMB;
  float acc = 0.f;
#pragma unroll 8
  for (int d = 0; d < DEMB; ++d) acc = fmaf(wrow[d], src[2 * d], acc);
  WbT[(long)(512 + lane) * DIN + k] = f2bf(acc);
}

// ---------- kernel 0d: bfold[j] = bb @ W34[:,j] + bias34[j] ----------
__global__ void bfold_k(const float* __restrict__ bb, const float* __restrict__ Wp,
                        const float* __restrict__ bp, const float* __restrict__ Ws,
                        const float* __restrict__ bs, float* __restrict__ bf) {
  int j = threadIdx.x;
  if (j >= 34) return;
  const float* src; float bias;
  if (j < 2) { src = Wp + j; bias = bp[j]; }
  else { int s = (j - 2) >> 1; src = Ws + s * 1024 + (j & 1); bias = bs[s * 2 + (j & 1)]; }
  float acc = bias;
  for (int d = 0; d < DEMB; ++d) acc = fmaf(bb[d], src[2 * d], acc);
  bf[j] = acc;
}

#define SB __builtin_amdgcn_sched_barrier(0)

// ---------- kernel 1: fused GEMM, wave-private dataflow (ZERO barriers in K-loop) ----------
// 128x128 block tile, BK=32, 4 waves (2x2). Each wave privately stages its own
// 64x64 operand slices into its own 16KB LDS region (A dbuf 2x4K via reg+pkhi,
// B dbuf 2x4K via gload_lds). Same-wave write->read ordered by counted
// s_waitcnt only. A prefetch 2 phases deep, B 1 deep; ONE vmcnt(12) per phase.
__global__ __launch_bounds__(256, 2) void gemm_fused(
    const float* __restrict__ x, const unsigned short* __restrict__ wbt,
    const float* __restrict__ bb, const int* __restrict__ sid,
    const float* __restrict__ bfold, float* __restrict__ out) {
  __shared__ __align__(16) char SM[65536];   // 4 waves x 16KB: A0|A1|B0|B1 (4KB each)

  const int t = threadIdx.x;
  const int lane = t & 63;
  const int wid = t >> 6;
  const int wm = wid >> 1, wn = wid & 1;

  char* const WP = SM + wid * 16384;
  char* const Al0 = WP;
  char* const Al1 = WP + 4096;
  char* const Bl0 = WP + 8192;
  char* const Bl1 = WP + 12288;

  // XCD swizzle: 5120 blocks (%8==0); 5 consecutive swz share one mtile/XCD.
  const int bid = blockIdx.x;
  const int swz = (bid & 7) * 640 + (bid >> 3);
  const int mtile = swz / 5;
  const int ntile = swz - mtile * 5;
  const long m0 = (long)mtile * 128;
  const int n0 = ntile * 128;

  // ---- A private staging: lane covers slice-row p*8+(lane>>3), f32-granule lane&7 ----
  // LDS write: b64 at row*64 + ((g2 ^ f)<<4) + half*8 ; g2=(lane&7)>>1, half=lane&1,
  // f(row)=(row>>1)&3 == (lane>>4)&3 (lane-uniform across p).
  const int awbyte = (lane >> 3) * 64 + (((((lane & 7) >> 1) ^ ((lane >> 4) & 3)) << 4))
                     + (lane & 1) * 8;                         // + p*512
  const float* xw = x + (m0 + wm * 64 + (lane >> 3)) * DIN + (lane & 7) * 4;

  // ---- B private staging (gload_lds linear dest, pre-swizzled src) ----
  // dest granule G=i*64+lane -> col n=G>>2, phys g=G&3; src g = (lane&3)^((lane>>3)&3)
  const unsigned short* bsrc =
      wbt + (long)(n0 + wn * 64 + (lane >> 2)) * DIN + ((lane & 3) ^ ((lane >> 3) & 3)) * 8;

  // ---- fragment reads: phys granule = lg ^ ((l15>>1)&3), 64B rows ----
  const int l15 = lane & 15, lg = lane >> 4;
  const int kgo = ((lg ^ ((l15 >> 1) & 3)) << 4);

  f32x4 acc[4][4] = {};
  float4 aE[8], aO[8];

  auto loadA = [&](float4* d, int k0) {      // 8 x dwordx4, dense (8 lanes/row)
#pragma unroll
    for (int p = 0; p < 8; ++p)
      d[p] = *(const float4*)(xw + (long)p * 8 * DIN + k0);
  };
  auto gloadB = [&](char* Bw, int k0) {      // 4 x gload_lds 16B (private slot)
#pragma unroll
    for (int i = 0; i < 4; ++i) {
      const unsigned short* gp = bsrc + (long)i * 16 * DIN + k0;
      __builtin_amdgcn_global_load_lds(
          (const __attribute__((address_space(1))) void*)gp,
          (__attribute__((address_space(3))) void*)(Bw + i * 1024), 16, 0, 0);
    }
  };
  auto writeA = [&](char* Aw, const float4* d) {   // 8 x ds_write_b64 (pkhi)
#pragma unroll
    for (int p = 0; p < 8; ++p) {
      uint2 v;
      v.x = pkhi(d[p].x, d[p].y);
      v.y = pkhi(d[p].z, d[p].w);
      *(uint2*)(Aw + awbyte + p * 512) = v;
    }
  };
  auto compute = [&](const char* Ac, const char* Bc) {
    bf16x8 af[4], bfv[4];
#pragma unroll
    for (int i = 0; i < 4; ++i) {
      af[i]  = *(const bf16x8*)(Ac + (l15 + i * 16) * 64 + kgo);
      bfv[i] = *(const bf16x8*)(Bc + (l15 + i * 16) * 64 + kgo);
    }
    SB;
    asm volatile("s_waitcnt lgkmcnt(0)" ::: "memory");
    SB;
    __builtin_amdgcn_s_setprio(1);
#pragma unroll
    for (int mi = 0; mi < 4; ++mi)
#pragma unroll
      for (int ni = 0; ni < 4; ++ni)
        acc[mi][ni] = __builtin_amdgcn_mfma_f32_16x16x32_bf16(af[mi], bfv[ni],
                                                             acc[mi][ni], 0, 0, 0);
    __builtin_amdgcn_s_setprio(0);
  };

  // phase s: loadA(s+2), gloadB(s+1), vmcnt(12) [drains A(s+1) regs + B(s)],
  // read+MFMA tile s, writeA(s+1).
#define PHASE(ALD, AWR, ALR, ALW, BST, BRD, KA, KB)                 \
  loadA(ALD, (KA) * 32);                                            \
  gloadB(BST, (KB) * 32);                                           \
  SB; asm volatile("s_waitcnt vmcnt(12) lgkmcnt(0)" ::: "memory"); SB; \
  compute(ALR, BRD);                                                \
  writeA(ALW, AWR);

  // ---- prologue (per wave, no barriers) ----
  loadA(aE, 0);                              // A(0): 8
  gloadB(Bl0, 0);                            // B(0): 4
  loadA(aO, 32);                             // A(1): 8
  SB; asm volatile("s_waitcnt vmcnt(12)" ::: "memory"); SB;   // A(0) done
  writeA(Al0, aE);

  // ---- main loop: s = 0..29, unroll x2 (static parities) ----
#pragma unroll 1
  for (int s2 = 0; s2 < 30; s2 += 2) {
    PHASE(aE, aO, Al0, Al1, Bl1, Bl0, s2 + 2, s2 + 1)        // even s
    PHASE(aO, aE, Al1, Al0, Bl0, Bl1, s2 + 3, s2 + 2)        // odd s
  }
  // ---- tail s=30: no loadA; stage B(31); write A(31) needs vmcnt(4) ----
  gloadB(Bl1, 31 * 32);
  SB; asm volatile("s_waitcnt vmcnt(12) lgkmcnt(0)" ::: "memory"); SB;  // B(30) done
  compute(Al0, Bl0);
  SB; asm volatile("s_waitcnt vmcnt(4)" ::: "memory"); SB;              // A(31) regs done
  writeA(Al1, aO);
  // ---- tail s=31 ----
  SB; asm volatile("s_waitcnt vmcnt(0) lgkmcnt(0)" ::: "memory"); SB;   // B(31)+writes done
  compute(Al1, Bl1);
#undef PHASE

  // ---- epilogue ----
  if (ntile < 4) {
    const int colg = n0 + wn * 64 + l15;
    float bbv[4];
#pragma unroll
    for (int ni = 0; ni < 4; ++ni) bbv[ni] = bb[colg + ni * 16];
#pragma unroll
    for (int mi = 0; mi < 4; ++mi) {
      const long rbase = m0 + wm * 64 + mi * 16 + lg * 4;
#pragma unroll
      for (int ni = 0; ni < 4; ++ni)
#pragma unroll
        for (int r = 0; r < 4; ++r)
          out[(rbase + r) * DEMB + colg + ni * 16] = acc[mi][ni][r] + bbv[ni];
    }
  } else {
    // head tile: acc cols 0..33 are x@Wfold; gather per-row selected cols via LDS
    __syncthreads();
    float* hl = (float*)SM;                  // [128][35] f32 = 17.5 KiB overlay
    if (wn == 0) {
#pragma unroll
      for (int ni = 0; ni < 3; ++ni) {
#pragma unroll
        for (int mi = 0; mi < 4; ++mi)
#pragma unroll
          for (int r = 0; r < 4; ++r) {
            int row = wm * 64 + mi * 16 + lg * 4 + r;
            int col = l15 + ni * 16;
            if (col < 35) hl[row * 35 + col] = acc[mi][ni][r];
          }
      }
    }
    __syncthreads();
    if (t < 128) {
      const long row = m0 + t;
      const int s = sid[row];
      const float v0 = hl[t * 35 + 0] + bfold[0];
      const float v1 = hl[t * 35 + 1] + bfold[1];
      const float v2 = hl[t * 35 + 2 + 2 * s] + bfold[2 + 2 * s];
      const float v3 = hl[t * 35 + 3 + 2 * s] + bfold[3 + 2 * s];
      float* hp = out + NROWS * DEMB;
      hp[row] = v0;
      hp[NROWS + row] = softplusf(v1) + 0.001f;
      hp[2 * NROWS + row] = v2;
      hp[3 * NROWS + row] = softplusf(v3) + 0.001f;
    }
  }
}

extern "C" void kernel_launch(void* const* d_in, const int* in_sizes, int n_in,
                              void* d_out, int out_size, void* d_ws, size_t ws_size,
                              hipStream_t stream) {
  const float* x  = (const float*)d_in[0];
  const int* sid  = (const int*)d_in[1];
  const float* Wb = (const float*)d_in[2];
  const float* bb = (const float*)d_in[3];
  const float* Wp = (const float*)d_in[4];
  const float* bp = (const float*)d_in[5];
  const float* Ws = (const float*)d_in[6];
  const float* bs = (const float*)d_in[7];
  float* out = (float*)d_out;
  unsigned short* WbT = (unsigned short*)d_ws;            // 640*1024 bf16 = 1.25 MiB
  float* bfoldp = (float*)(WbT + (long)NEXT * DIN);       // 34 f32

  wb_transpose<<<256, 256, 0, stream>>>(Wb, WbT);
  zero_tail<<<188, 256, 0, stream>>>((unsigned*)(WbT + 546 * DIN));
  wfold_rows<<<256, 256, 0, stream>>>(Wb, Wp, Ws, WbT);
  bfold_k<<<1, 64, 0, stream>>>(bb, Wp, bp, Ws, bs, bfoldp);
  gemm_fused<<<5120, 256, 0, stream>>>(x, WbT, bb, sid, bfoldp, out);
}

// Round 13
// 341.669 us; speedup vs baseline: 1.4510x; 1.4510x over previous
//
#include <hip/hip_runtime.h>

typedef short bf16x8 __attribute__((ext_vector_type(8)));
typedef float f32x4 __attribute__((ext_vector_type(4)));

#define NROWS 131072L
#define DIN 1024
#define DEMB 512
#define NEXT 640   // extended B rows: 512 emb + 34 folded-head + zero tail

__device__ __forceinline__ unsigned short f2bf(float f) {
  unsigned u = __float_as_uint(f);
  u += 0x7FFFu + ((u >> 16) & 1u);
  return (unsigned short)(u >> 16);
}

// Pack two f32 -> two bf16 (round-half-up): 2 adds + 1 v_perm_b32 (R5+-proven).
__device__ __forceinline__ unsigned pkhi(float a, float b) {
  unsigned ua = __float_as_uint(a) + 0x8000u;
  unsigned ub = __float_as_uint(b) + 0x8000u;
  return __builtin_amdgcn_perm(ub, ua, 0x07060302u);
}

__device__ __forceinline__ float softplusf(float v) {
  return fmaxf(v, 0.f) + log1pf(expf(-fabsf(v)));
}

// ---------- kernel 0: Wb (1024x512 f32) -> WbT rows 0..511 (bf16, k-contig) ----------
__global__ __launch_bounds__(256) void wb_transpose(const float* __restrict__ Wb,
                                                    unsigned short* __restrict__ WbT) {
  int g = blockIdx.x * 256 + threadIdx.x;
  int n = g & 511;
  int kb = g >> 9;
  unsigned short tmp[8];
#pragma unroll
  for (int j = 0; j < 8; ++j)
    tmp[j] = f2bf(Wb[(kb * 8 + j) * DEMB + n]);
  uint4 v;
  v.x = (unsigned)tmp[0] | ((unsigned)tmp[1] << 16);
  v.y = (unsigned)tmp[2] | ((unsigned)tmp[3] << 16);
  v.z = (unsigned)tmp[4] | ((unsigned)tmp[5] << 16);
  v.w = (unsigned)tmp[6] | ((unsigned)tmp[7] << 16);
  *(uint4*)(WbT + (long)n * DIN + kb * 8) = v;
}

// ---------- kernel 0b: zero rows 546..639 of WbT_ext ----------
__global__ void zero_tail(unsigned* __restrict__ p) {
  p[blockIdx.x * 256 + threadIdx.x] = 0u;
}

// ---------- kernel 0c: WbT rows 512..545 = (Wb @ W34)^T ----------
__global__ __launch_bounds__(256) void wfold_rows(const float* __restrict__ Wb,
                                                  const float* __restrict__ Wp,
                                                  const float* __restrict__ Ws,
                                                  unsigned short* __restrict__ WbT) {
  int w = threadIdx.x >> 6, lane = threadIdx.x & 63;
  int k = blockIdx.x * 4 + w;
  if (lane >= 34) return;
  const float* src;
  if (lane < 2) src = Wp + lane;
  else { int s = (lane - 2) >> 1; src = Ws + s * 1024 + (lane & 1); }
  const float* wrow = Wb + (long)k * DEMB;
  float acc = 0.f;
#pragma unroll 8
  for (int d = 0; d < DEMB; ++d) acc = fmaf(wrow[d], src[2 * d], acc);
  WbT[(long)(512 + lane) * DIN + k] = f2bf(acc);
}

// ---------- kernel 0d: bfold[j] = bb @ W34[:,j] + bias34[j] ----------
__global__ void bfold_k(const float* __restrict__ bb, const float* __restrict__ Wp,
                        const float* __restrict__ bp, const float* __restrict__ Ws,
                        const float* __restrict__ bs, float* __restrict__ bf) {
  int j = threadIdx.x;
  if (j >= 34) return;
  const float* src; float bias;
  if (j < 2) { src = Wp + j; bias = bp[j]; }
  else { int s = (j - 2) >> 1; src = Ws + s * 1024 + (j & 1); bias = bs[s * 2 + (j & 1)]; }
  float acc = bias;
  for (int d = 0; d < DEMB; ++d) acc = fmaf(bb[d], src[2 * d], acc);
  bf[j] = acc;
}

#define SB __builtin_amdgcn_sched_barrier(0)

// ---------- kernel 1: fused GEMM — BK=64, depth-2 A prefetch, counted vmcnt ----------
// 128x128 tile, BK=64 (16 phases, half the barriers of R10), 2x2 waves.
// Per phase t: issue B(t+1) [4 gload_lds] + A(t+2) [8 dwordx4]; compute tile t
// (16 ds_read + 32 MFMA, compiler fine-grained lgkmcnt); vmcnt(12) -> A(t+1)
// regs landed -> pkhi+writeA; vmcnt(8)+lgkm0 -> B(t+1) in LDS; barrier.
// A-loads get ~1.5 phases (>1500cy) of flight; B a full phase (~1200cy).
__global__ __launch_bounds__(256, 2) void gemm_fused(
    const float* __restrict__ x, const unsigned short* __restrict__ wbt,
    const float* __restrict__ bb, const int* __restrict__ sid,
    const float* __restrict__ bfold, float* __restrict__ out) {
  __shared__ __align__(16) char SM[65536];   // As0|As1|Bs0|Bs1, 16 KB each
  char* const As0 = SM;
  char* const As1 = SM + 16384;
  char* const Bs0 = SM + 32768;
  char* const Bs1 = SM + 49152;

  const int t = threadIdx.x;
  const int lane = t & 63;
  const int wid = t >> 6;
  const int wm = wid >> 1, wn = wid & 1;

  // XCD swizzle: 5120 blocks (%8==0); 5 consecutive swz share one mtile/XCD.
  const int bid = blockIdx.x;
  const int swz = (bid & 7) * 640 + (bid >> 3);
  const int mtile = swz / 5;
  const int ntile = swz - mtile * 5;         // 0..3 emb, 4 = head
  const long m0 = (long)mtile * 128;
  const int n0 = ntile * 128;

  // ---- A staging (R1-proven BK=64 pattern): row = t>>4 (+p*16), 16B-col t&15 ----
  const int arow = t >> 4;
  const int acol8 = (t & 15) * 8;            // byte col within 128B row
  const int abyte = arow * 128 + (acol8 ^ ((arow & 7) << 4));   // +p*2048
  const float* xbase = x + (m0 + arow) * DIN + (t & 15) * 4;

  // ---- B staging (R1-proven): gload_lds, pre-swizzled source ----
  const int bn = wid * 32 + (lane >> 3);     // +i*8
  const int bg = (lane & 7) ^ (lane >> 3);
  const unsigned short* bsrc = wbt + (long)(n0 + bn) * DIN + bg * 8;

  // ---- fragment reads (R1-proven): granule = (ks*4+lg) ^ (l15&7), 128B rows ----
  const int l15 = lane & 15, lg = lane >> 4;
  const int s3 = lane & 7;
  const int kg0 = ((lg ^ s3) << 4);          // ks=1 -> ^64
  const int ardrow = (wm * 64 + l15) * 128;
  const int brdrow = (wn * 64 + l15) * 128;

  f32x4 acc[4][4] = {};
  float4 aA[8], aB[8];                       // A(k): k even -> aA, k odd -> aB

  auto loadA = [&](float4* d, int k0) {      // 8 x dwordx4, dense 256B/row-segment
#pragma unroll
    for (int p = 0; p < 8; ++p)
      d[p] = *(const float4*)(xbase + (long)p * 16 * DIN + k0);
  };
  auto stageB = [&](char* Bw, int k0) {      // 4 x gload_lds 16B
#pragma unroll
    for (int i = 0; i < 4; ++i) {
      const unsigned short* gp = bsrc + (long)i * 8 * DIN + k0;
      __builtin_amdgcn_global_load_lds(
          (const __attribute__((address_space(1))) void*)gp,
          (__attribute__((address_space(3))) void*)(Bw + wid * 4096 + i * 1024),
          16, 0, 0);
    }
  };
  auto writeA = [&](char* Aw, const float4* d) {   // 8 x ds_write_b64 (pkhi)
#pragma unroll
    for (int p = 0; p < 8; ++p) {
      uint2 v;
      v.x = pkhi(d[p].x, d[p].y);
      v.y = pkhi(d[p].z, d[p].w);
      *(uint2*)(Aw + abyte + p * 2048) = v;
    }
  };
  auto compute = [&](const char* Ac, const char* Bc) {   // 16 ds_read + 32 MFMA
#pragma unroll
    for (int ks = 0; ks < 2; ++ks) {
      const int kgo = kg0 ^ (ks << 6);
      bf16x8 af[4], bfv[4];
#pragma unroll
      for (int i = 0; i < 4; ++i) {
        af[i]  = *(const bf16x8*)(Ac + ardrow + i * 2048 + kgo);
        bfv[i] = *(const bf16x8*)(Bc + brdrow + i * 2048 + kgo);
      }
      __builtin_amdgcn_s_setprio(1);
#pragma unroll
      for (int mi = 0; mi < 4; ++mi)
#pragma unroll
        for (int ni = 0; ni < 4; ++ni)
          acc[mi][ni] = __builtin_amdgcn_mfma_f32_16x16x32_bf16(af[mi], bfv[ni],
                                                               acc[mi][ni], 0, 0, 0);
      __builtin_amdgcn_s_setprio(0);
    }
  };

  // ---- prologue ----
  loadA(aA, 0);                              // A(0): 8
  stageB(Bs0, 0);                            // B(0): 4
  SB; asm volatile("s_waitcnt vmcnt(4)" ::: "memory"); SB;    // A(0) regs landed
  writeA(As0, aA);
  loadA(aB, 64);                             // A(1): 8 in flight
  SB; asm volatile("s_waitcnt vmcnt(8) lgkmcnt(0)" ::: "memory"); SB;  // B(0) in LDS
  __builtin_amdgcn_s_barrier();

  // ---- main loop: phases 0..13, unroll x2 (static parities) ----
#pragma unroll 1
  for (int tb = 0; tb < 14; tb += 2) {
    // EVEN phase tb: compute As0/Bs0; B(tb+1)->Bs1; A(tb+2)->aA; write A(tb+1)=aB->As1
    stageB(Bs1, (tb + 1) * 64);
    loadA(aA, (tb + 2) * 64);
    compute(As0, Bs0);
    SB; asm volatile("s_waitcnt vmcnt(12)" ::: "memory"); SB;    // A(tb+1) regs landed
    writeA(As1, aB);
    SB; asm volatile("s_waitcnt vmcnt(8) lgkmcnt(0)" ::: "memory"); SB;  // B(tb+1) in LDS
    __builtin_amdgcn_s_barrier();
    // ODD phase tb+1: compute As1/Bs1; B(tb+2)->Bs0; A(tb+3)->aB; write A(tb+2)=aA->As0
    stageB(Bs0, (tb + 2) * 64);
    loadA(aB, (tb + 3) * 64);
    compute(As1, Bs1);
    SB; asm volatile("s_waitcnt vmcnt(12)" ::: "memory"); SB;
    writeA(As0, aA);
    SB; asm volatile("s_waitcnt vmcnt(8) lgkmcnt(0)" ::: "memory"); SB;
    __builtin_amdgcn_s_barrier();
  }

  // ---- phase 14 (no A-issue): stage B(15); compute 14; write A(15)=aB ----
  stageB(Bs1, 15 * 64);
  compute(As0, Bs0);
  SB; asm volatile("s_waitcnt vmcnt(4)" ::: "memory"); SB;     // A(15) regs landed
  writeA(As1, aB);
  SB; asm volatile("s_waitcnt vmcnt(0) lgkmcnt(0)" ::: "memory"); SB;   // B(15) in LDS
  __builtin_amdgcn_s_barrier();
  // ---- phase 15 ----
  compute(As1, Bs1);

  // ---- epilogue ----
  if (ntile < 4) {
    const int colg = n0 + wn * 64 + l15;
    float bbv[4];
#pragma unroll
    for (int ni = 0; ni < 4; ++ni) bbv[ni] = bb[colg + ni * 16];
#pragma unroll
    for (int mi = 0; mi < 4; ++mi) {
      const long rbase = m0 + wm * 64 + mi * 16 + lg * 4;
#pragma unroll
      for (int ni = 0; ni < 4; ++ni)
#pragma unroll
        for (int r = 0; r < 4; ++r)
          out[(rbase + r) * DEMB + colg + ni * 16] = acc[mi][ni][r] + bbv[ni];
    }
  } else {
    // head tile: acc cols 0..33 are x@Wfold; gather per-row selected cols via LDS
    __syncthreads();
    float* hl = (float*)SM;                  // [128][35] f32 = 17.5 KiB overlay
    if (wn == 0) {
#pragma unroll
      for (int ni = 0; ni < 3; ++ni) {
#pragma unroll
        for (int mi = 0; mi < 4; ++mi)
#pragma unroll
          for (int r = 0; r < 4; ++r) {
            int row = wm * 64 + mi * 16 + lg * 4 + r;
            int col = l15 + ni * 16;
            if (col < 35) hl[row * 35 + col] = acc[mi][ni][r];
          }
      }
    }
    __syncthreads();
    if (t < 128) {
      const long row = m0 + t;
      const int s = sid[row];
      const float v0 = hl[t * 35 + 0] + bfold[0];
      const float v1 = hl[t * 35 + 1] + bfold[1];
      const float v2 = hl[t * 35 + 2 + 2 * s] + bfold[2 + 2 * s];
      const float v3 = hl[t * 35 + 3 + 2 * s] + bfold[3 + 2 * s];
      float* hp = out + NROWS * DEMB;
      hp[row] = v0;
      hp[NROWS + row] = softplusf(v1) + 0.001f;
      hp[2 * NROWS + row] = v2;
      hp[3 * NROWS + row] = softplusf(v3) + 0.001f;
    }
  }
}

extern "C" void kernel_launch(void* const* d_in, const int* in_sizes, int n_in,
                              void* d_out, int out_size, void* d_ws, size_t ws_size,
                              hipStream_t stream) {
  const float* x  = (const float*)d_in[0];
  const int* sid  = (const int*)d_in[1];
  const float* Wb = (const float*)d_in[2];
  const float* bb = (const float*)d_in[3];
  const float* Wp = (const float*)d_in[4];
  const float* bp = (const float*)d_in[5];
  const float* Ws = (const float*)d_in[6];
  const float* bs = (const float*)d_in[7];
  float* out = (float*)d_out;
  unsigned short* WbT = (unsigned short*)d_ws;            // 640*1024 bf16 = 1.25 MiB
  float* bfoldp = (float*)(WbT + (long)NEXT * DIN);       // 34 f32

  wb_transpose<<<256, 256, 0, stream>>>(Wb, WbT);
  zero_tail<<<188, 256, 0, stream>>>((unsigned*)(WbT + 546 * DIN));
  wfold_rows<<<256, 256, 0, stream>>>(Wb, Wp, Ws, WbT);
  bfold_k<<<1, 64, 0, stream>>>(bb, Wp, bp, Ws, bs, bfoldp);
  gemm_fused<<<5120, 256, 0, stream>>>(x, WbT, bb, sid, bfoldp, out);
}